// Round 1
// baseline (4202.656 us; speedup 1.0000x reference)
//
#include <hip/hip_runtime.h>

#define B_ 64
#define P_ 196
#define ENC_ 2048
#define L_ 20
#define T_ 19
#define A_ 512
#define D_ 512
#define E_ 512
#define V_ 10000
#define KIH_ 2560
#define G4_ 2048

// output offsets (float elements)
#define OFF_PREDS 0
#define OFF_CAPS  12160000
#define OFF_DLEN  12161280
#define OFF_ALPH  12161344
#define OFF_SIDX  12399680

// workspace offsets (bytes); total ~43.5 MB
#define WS_SORT  0
#define WS_DLEN  1024
#define WS_CAPS  2048
#define WS_RIDXE 8192
#define WS_RIDXM 61440
#define WS_MEAN  131072
#define WS_H     655360
#define WS_C     786432
#define WS_PH    917504
#define WS_PC    1966080
#define WS_EPT   3014656
#define WS_GEMB  28704768
#define WS_ALPHA 38666240
#define WS_CTXG  38716416
#define WS_GPART 39240704

__device__ __forceinline__ float ftanh(float x){ float e=__expf(2.f*x); return 1.f-2.f/(e+1.f); }
__device__ __forceinline__ float fsigm(float x){ return 1.f/(1.f+__expf(-x)); }

// ---------------------------------------------------------------- sort + meta
__global__ void k_sort(const int* __restrict__ cap_len, const int* __restrict__ captions,
                       float* __restrict__ out, int* __restrict__ wsi)
{
    __shared__ int len_s[B_];
    __shared__ int idx_s[B_];
    int tid = threadIdx.x;
    if (tid < B_) { len_s[tid] = cap_len[tid]; idx_s[tid] = tid; }
    __syncthreads();
    if (tid == 0) {
        // stable descending-by-length selection sort (ties: ascending orig idx)
        for (int i = 0; i < B_; ++i) {
            int best = i;
            for (int j = i + 1; j < B_; ++j) {
                if (len_s[j] > len_s[best] ||
                    (len_s[j] == len_s[best] && idx_s[j] < idx_s[best])) best = j;
            }
            int tl = len_s[i]; len_s[i] = len_s[best]; len_s[best] = tl;
            int ti = idx_s[i]; idx_s[i] = idx_s[best]; idx_s[best] = ti;
        }
    }
    __syncthreads();
    int* sortidx = wsi + WS_SORT / 4;
    int* dlen    = wsi + WS_DLEN / 4;
    int* caps    = wsi + WS_CAPS / 4;
    int* ridxe   = wsi + WS_RIDXE / 4;
    int* ridxm   = wsi + WS_RIDXM / 4;
    if (tid < B_) {
        sortidx[tid] = idx_s[tid];
        int dl = len_s[tid] - 1;
        dlen[tid] = dl;
        out[OFF_SIDX + tid] = (float)idx_s[tid];
        out[OFF_DLEN + tid] = (float)dl;
        for (int l = 0; l < L_; ++l) {
            int cv = captions[idx_s[tid] * L_ + l];
            caps[tid * L_ + l] = cv;
            out[OFF_CAPS + tid * L_ + l] = (float)cv;
        }
    }
    for (int i = tid; i < B_ * P_; i += blockDim.x) {
        int bb = i / P_, pp = i % P_;
        ridxe[i] = idx_s[bb] * P_ + pp;
    }
    for (int i = tid; i < B_ * T_; i += blockDim.x) {
        int bb = i / T_, tt = i % T_;
        ridxm[i] = captions[idx_s[bb] * L_ + tt];
    }
}

// ---------------------------------------------------------------- mean feats
__global__ __launch_bounds__(256) void k_mean(const float* __restrict__ enc,
                                              const int* __restrict__ wsi,
                                              float* __restrict__ mean)
{
    int b = blockIdx.x;
    int e = blockIdx.y * 256 + threadIdx.x;
    int src = wsi[WS_SORT / 4 + b];
    const float* p = enc + (long)src * P_ * ENC_ + e;
    float s = 0.f;
    for (int i = 0; i < P_; ++i) s += p[(long)i * ENC_];
    mean[b * ENC_ + e] = s * (1.f / (float)P_);
}

// ---------------------------------------------------------------- generic tiled GEMM
// BLAY: 0 = B[k*ldb+n] (KN), 1 = B[n*ldb+k] (NK)
// EPI : 0 = enc_projT: C[b][n][p] (b=gm/196,p=gm%196), bias
//       1 = gates_emb: C[(tt*64+b)*2048+n] (b=gm/19,tt=gm%19), bias+bias2
template<int BLAY, int EPI>
__global__ __launch_bounds__(256) void k_gemm(
    const float* __restrict__ A, int lda, const int* __restrict__ rowidx,
    const float* __restrict__ Bmat, int ldb,
    const float* __restrict__ bias, const float* __restrict__ bias2,
    float* __restrict__ C, int N, int K)
{
    __shared__ float As[16][68];
    __shared__ float Bs[16][68];
    int tid = threadIdx.x;
    int n0 = blockIdx.x * 64;
    int m0 = blockIdx.y * 64;
    int tx = tid & 15, ty = tid >> 4;
    float acc[4][4] = {};
    int am = tid >> 2, akq = (tid & 3) << 2;
    long arow = (long)(rowidx ? rowidx[m0 + am] : (m0 + am)) * lda;
    for (int k0 = 0; k0 < K; k0 += 16) {
        float4 av = *(const float4*)(A + arow + k0 + akq);
        As[akq + 0][am] = av.x; As[akq + 1][am] = av.y;
        As[akq + 2][am] = av.z; As[akq + 3][am] = av.w;
        if (BLAY == 0) {
            int bk = tid >> 4, bnq = (tid & 15) << 2;
            float4 bv = *(const float4*)(Bmat + (long)(k0 + bk) * ldb + n0 + bnq);
            Bs[bk][bnq + 0] = bv.x; Bs[bk][bnq + 1] = bv.y;
            Bs[bk][bnq + 2] = bv.z; Bs[bk][bnq + 3] = bv.w;
        } else {
            int bn = tid >> 2, bkq = (tid & 3) << 2;
            int gn = n0 + bn;
            float4 bv = make_float4(0.f, 0.f, 0.f, 0.f);
            if (gn < N) bv = *(const float4*)(Bmat + (long)gn * ldb + k0 + bkq);
            Bs[bkq + 0][bn] = bv.x; Bs[bkq + 1][bn] = bv.y;
            Bs[bkq + 2][bn] = bv.z; Bs[bkq + 3][bn] = bv.w;
        }
        __syncthreads();
#pragma unroll
        for (int kk = 0; kk < 16; ++kk) {
            float4 a4 = *(const float4*)&As[kk][ty << 2];
            float4 b4 = *(const float4*)&Bs[kk][tx << 2];
            float aa[4] = {a4.x, a4.y, a4.z, a4.w};
            float bb[4] = {b4.x, b4.y, b4.z, b4.w};
#pragma unroll
            for (int i = 0; i < 4; ++i)
#pragma unroll
                for (int j = 0; j < 4; ++j) acc[i][j] += aa[i] * bb[j];
        }
        __syncthreads();
    }
#pragma unroll
    for (int i = 0; i < 4; ++i) {
        int gm = m0 + (ty << 2) + i;
#pragma unroll
        for (int j = 0; j < 4; ++j) {
            int gn = n0 + (tx << 2) + j;
            if (gn >= N) continue;
            float v = acc[i][j];
            if (bias)  v += bias[gn];
            if (bias2) v += bias2[gn];
            if (EPI == 0) {
                int bq = gm / P_, pq = gm % P_;
                C[(long)bq * (A_ * P_) + gn * P_ + pq] = v;
            } else {
                int bq = gm / T_, tq = gm % T_;
                C[((long)(tq * B_ + bq)) * G4_ + gn] = v;
            }
        }
    }
}

// ---------------------------------------------------------------- skinny M=64 split-K GEMM
// BLAY as above; EPI: 0 = partial[(split*64+m)*N+n], 1 = pred direct (bias+mask)
template<int BLAY, int EPI>
__global__ __launch_bounds__(256) void k_skinny(
    const float* __restrict__ A1, int lda1,
    const float* __restrict__ B1, int ldb1,
    int Ksw,
    const float* __restrict__ A2, int lda2,
    const float* __restrict__ B2, int ldb2,
    int N, int Ktot, int Kper,
    float* __restrict__ Cout, const float* __restrict__ bias,
    int t, const int* __restrict__ dlen)
{
    __shared__ float As[16][68];
    __shared__ float Bs[16][68];
    int tid = threadIdx.x;
    int n0 = blockIdx.x * 64;
    int split = blockIdx.y;
    int kbeg = split * Kper;
    int kend = kbeg + Kper; if (kend > Ktot) kend = Ktot;
    int tx = tid & 15, ty = tid >> 4;
    float acc[4][4] = {};
    int am = tid >> 2, akq = (tid & 3) << 2;
    for (int k0 = kbeg; k0 < kend; k0 += 16) {
        const float* Aseg; int ldaS; const float* Bseg; int ldbS; int ks;
        if (k0 < Ksw) { Aseg = A1; ldaS = lda1; Bseg = B1; ldbS = ldb1; ks = k0; }
        else          { Aseg = A2; ldaS = lda2; Bseg = B2; ldbS = ldb2; ks = k0 - Ksw; }
        float4 av = *(const float4*)(Aseg + (long)am * ldaS + ks + akq);
        As[akq + 0][am] = av.x; As[akq + 1][am] = av.y;
        As[akq + 2][am] = av.z; As[akq + 3][am] = av.w;
        if (BLAY == 0) {
            int bk = tid >> 4, bnq = (tid & 15) << 2;
            float4 bv = *(const float4*)(Bseg + (long)(ks + bk) * ldbS + n0 + bnq);
            Bs[bk][bnq + 0] = bv.x; Bs[bk][bnq + 1] = bv.y;
            Bs[bk][bnq + 2] = bv.z; Bs[bk][bnq + 3] = bv.w;
        } else {
            int bn = tid >> 2, bkq = (tid & 3) << 2;
            int gn = n0 + bn;
            float4 bv = make_float4(0.f, 0.f, 0.f, 0.f);
            if (gn < N) bv = *(const float4*)(Bseg + (long)gn * ldbS + ks + bkq);
            Bs[bkq + 0][bn] = bv.x; Bs[bkq + 1][bn] = bv.y;
            Bs[bkq + 2][bn] = bv.z; Bs[bkq + 3][bn] = bv.w;
        }
        __syncthreads();
#pragma unroll
        for (int kk = 0; kk < 16; ++kk) {
            float4 a4 = *(const float4*)&As[kk][ty << 2];
            float4 b4 = *(const float4*)&Bs[kk][tx << 2];
            float aa[4] = {a4.x, a4.y, a4.z, a4.w};
            float bb[4] = {b4.x, b4.y, b4.z, b4.w};
#pragma unroll
            for (int i = 0; i < 4; ++i)
#pragma unroll
                for (int j = 0; j < 4; ++j) acc[i][j] += aa[i] * bb[j];
        }
        __syncthreads();
    }
#pragma unroll
    for (int i = 0; i < 4; ++i) {
        int m = (ty << 2) + i;
#pragma unroll
        for (int j = 0; j < 4; ++j) {
            int gn = n0 + (tx << 2) + j;
            if (gn >= N) continue;
            if (EPI == 0) {
                Cout[((long)(split * B_ + m)) * N + gn] = acc[i][j];
            } else {
                if (t < dlen[m])
                    Cout[((long)m * T_ + t) * V_ + gn] = acc[i][j] + bias[gn];
            }
        }
    }
}

// ---------------------------------------------------------------- h0/c0 reduce
__global__ __launch_bounds__(256) void k_reduce_hc(
    const float* __restrict__ ph, const float* __restrict__ pc,
    const float* __restrict__ bih, const float* __restrict__ bic,
    float* __restrict__ h, float* __restrict__ c)
{
    int i = blockIdx.x * 256 + threadIdx.x; // 64*512
    int d = i & (D_ - 1);
    float sh = bih[d], s2 = bic[d];
    for (int s = 0; s < 8; ++s) {
        sh += ph[(long)s * (B_ * D_) + i];
        s2 += pc[(long)s * (B_ * D_) + i];
    }
    h[i] = sh; c[i] = s2;
}

// ---------------------------------------------------------------- attention scores + softmax
__global__ __launch_bounds__(256) void k_attn(
    const float* __restrict__ h, const float* __restrict__ Wd, const float* __restrict__ bd,
    const float* __restrict__ wf, const float* __restrict__ bf,
    const float* __restrict__ ept, const int* __restrict__ dlen,
    float* __restrict__ alpha_ws, float* __restrict__ out, int t)
{
    int b = blockIdx.x;
    if (t >= dlen[b]) return;
    __shared__ float hs[D_];
    __shared__ float das[A_];
    __shared__ float wfs[A_];
    __shared__ float red[256];
    int tid = threadIdx.x;
    hs[tid] = h[b * D_ + tid]; hs[tid + 256] = h[b * D_ + tid + 256];
    wfs[tid] = wf[tid]; wfs[tid + 256] = wf[tid + 256];
    __syncthreads();
    for (int a = tid; a < A_; a += 256) {
        float v = bd[a];
        for (int k = 0; k < D_; ++k) v += hs[k] * Wd[k * A_ + a];
        das[a] = v;
    }
    __syncthreads();
    float sc = -1e30f;
    if (tid < P_) {
        sc = bf[0];
        const float* ep = ept + (long)b * (A_ * P_) + tid;
        for (int a = 0; a < A_; ++a) sc += wfs[a] * ftanh(ep[(long)a * P_] + das[a]);
    }
    red[tid] = (tid < P_) ? sc : -1e30f;
    __syncthreads();
    for (int s = 128; s > 0; s >>= 1) {
        if (tid < s) red[tid] = fmaxf(red[tid], red[tid + s]);
        __syncthreads();
    }
    float m = red[0];
    __syncthreads();
    float e = (tid < P_) ? __expf(sc - m) : 0.f;
    red[tid] = e;
    __syncthreads();
    for (int s = 128; s > 0; s >>= 1) {
        if (tid < s) red[tid] += red[tid + s];
        __syncthreads();
    }
    float inv = 1.f / red[0];
    if (tid < P_) {
        float al = e * inv;
        alpha_ws[b * P_ + tid] = al;
        out[OFF_ALPH + ((long)b * T_ + t) * P_ + tid] = al;
    }
}

// ---------------------------------------------------------------- gated context
__global__ __launch_bounds__(256) void k_ctx(
    const float* __restrict__ alpha, const float* __restrict__ h,
    const float* __restrict__ Wbe, const float* __restrict__ bbe,
    const float* __restrict__ enc, const int* __restrict__ wsi,
    const int* __restrict__ dlen, float* __restrict__ ctxg, int t)
{
    int b = blockIdx.x;
    if (t >= dlen[b]) return;
    __shared__ float als[P_];
    __shared__ float hs[D_];
    int tid = threadIdx.x;
    if (tid < P_) als[tid] = alpha[b * P_ + tid];
    hs[tid] = h[b * D_ + tid]; hs[tid + 256] = h[b * D_ + tid + 256];
    __syncthreads();
    int e = blockIdx.y * 256 + tid;
    float g = bbe[e];
    for (int k = 0; k < D_; ++k) g += hs[k] * Wbe[k * ENC_ + e];
    g = fsigm(g);
    int src = wsi[WS_SORT / 4 + b];
    const float* ep = enc + ((long)src * P_) * ENC_ + e;
    float cv = 0.f;
    for (int p = 0; p < P_; ++p) cv += als[p] * ep[(long)p * ENC_];
    ctxg[b * ENC_ + e] = g * cv;
}

// ---------------------------------------------------------------- LSTM pointwise (reduce gates partials)
__global__ __launch_bounds__(256) void k_lstm(
    const float* __restrict__ gemb, const float* __restrict__ gpart,
    const int* __restrict__ dlen, float* __restrict__ h, float* __restrict__ c, int t)
{
    int b = blockIdx.x;
    if (t >= dlen[b]) return;
    int d = blockIdx.y * 256 + threadIdx.x;
    const float* ge = gemb + ((long)(t * B_ + b)) * G4_;
    float g[4];
#pragma unroll
    for (int q = 0; q < 4; ++q) {
        int j = q * D_ + d;
        float v = ge[j];
        for (int s = 0; s < 8; ++s) v += gpart[((long)(s * B_ + b)) * G4_ + j];
        g[q] = v;
    }
    float i_ = fsigm(g[0]), f_ = fsigm(g[1]), gg = ftanh(g[2]), o_ = fsigm(g[3]);
    long off = (long)b * D_ + d;
    float cn = f_ * c[off] + i_ * gg;
    float hn = o_ * ftanh(cn);
    c[off] = cn; h[off] = hn;
}

// ---------------------------------------------------------------- launch
extern "C" void kernel_launch(void* const* d_in, const int* in_sizes, int n_in,
                              void* d_out, int out_size, void* d_ws, size_t ws_size,
                              hipStream_t stream)
{
    (void)in_sizes; (void)n_in; (void)out_size; (void)ws_size;
    const float* enc      = (const float*)d_in[0];
    const int*   captions = (const int*)d_in[1];
    const int*   caplen   = (const int*)d_in[2];
    const float* Wemb     = (const float*)d_in[3];
    const float* Wea = (const float*)d_in[4];  const float* bea = (const float*)d_in[5];
    const float* Wda = (const float*)d_in[6];  const float* bda = (const float*)d_in[7];
    const float* Wfa = (const float*)d_in[8];  const float* bfa = (const float*)d_in[9];
    const float* Wih = (const float*)d_in[10]; const float* bih = (const float*)d_in[11];
    const float* Wic = (const float*)d_in[12]; const float* bic = (const float*)d_in[13];
    const float* Wbe = (const float*)d_in[14]; const float* bbe = (const float*)d_in[15];
    const float* WIH = (const float*)d_in[16]; const float* bIH = (const float*)d_in[17];
    const float* WHH = (const float*)d_in[18]; const float* bHH = (const float*)d_in[19];
    const float* Wout = (const float*)d_in[20]; const float* bout = (const float*)d_in[21];

    float* out = (float*)d_out;
    char*  ws  = (char*)d_ws;
    int*   wsi = (int*)ws;
    float* mean  = (float*)(ws + WS_MEAN);
    float* h     = (float*)(ws + WS_H);
    float* c     = (float*)(ws + WS_C);
    float* ph    = (float*)(ws + WS_PH);
    float* pc    = (float*)(ws + WS_PC);
    float* ept   = (float*)(ws + WS_EPT);
    float* gemb  = (float*)(ws + WS_GEMB);
    float* alph  = (float*)(ws + WS_ALPHA);
    float* ctxg  = (float*)(ws + WS_CTXG);
    float* gpart = (float*)(ws + WS_GPART);
    const int* dlen = wsi + WS_DLEN / 4;

    // zero preds + alphas (masked entries stay 0)
    hipMemsetAsync(out, 0, (size_t)OFF_CAPS * 4, stream);
    hipMemsetAsync(out + OFF_ALPH, 0, (size_t)(B_ * T_ * P_) * 4, stream);

    k_sort<<<1, 64, 0, stream>>>(caplen, captions, out, wsi);
    k_mean<<<dim3(64, 8), 256, 0, stream>>>(enc, wsi, mean);
    // h0 / c0 partials (split-K 8 x 256)
    k_skinny<0, 0><<<dim3(8, 8), 256, 0, stream>>>(mean, ENC_, Wih, D_, 1 << 30,
        nullptr, 0, nullptr, 0, D_, ENC_, 256, ph, nullptr, 0, nullptr);
    k_skinny<0, 0><<<dim3(8, 8), 256, 0, stream>>>(mean, ENC_, Wic, D_, 1 << 30,
        nullptr, 0, nullptr, 0, D_, ENC_, 256, pc, nullptr, 0, nullptr);
    k_reduce_hc<<<128, 256, 0, stream>>>(ph, pc, bih, bic, h, c);
    // enc_projT: [b][a][p]
    k_gemm<0, 0><<<dim3(8, 196), 256, 0, stream>>>(enc, ENC_, wsi + WS_RIDXE / 4,
        Wea, A_, bea, nullptr, ept, A_, ENC_);
    // gates_emb: emb_t @ W_ih[:, :512] + b_ih + b_hh, laid out [t][b][j]
    k_gemm<1, 1><<<dim3(32, 19), 256, 0, stream>>>(Wemb, E_, wsi + WS_RIDXM / 4,
        WIH, KIH_, bIH, bHH, gemb, G4_, E_);

    for (int t = 0; t < T_; ++t) {
        k_attn<<<64, 256, 0, stream>>>(h, Wda, bda, Wfa, bfa, ept, dlen, alph, out, t);
        k_ctx<<<dim3(64, 8), 256, 0, stream>>>(alph, h, Wbe, bbe, enc, wsi, dlen, ctxg, t);
        // gates partials: ctx part (K=2048, W_ih[:,512:]) then h part (K=512, W_hh)
        k_skinny<1, 0><<<dim3(32, 8), 256, 0, stream>>>(ctxg, ENC_, WIH + E_, KIH_,
            ENC_, h, D_, WHH, D_, G4_, ENC_ + D_, 320, gpart, nullptr, t, nullptr);
        k_lstm<<<dim3(64, 2), 256, 0, stream>>>(gemb, gpart, dlen, h, c, t);
        // pred: h_new @ W_out.T + b_out, masked scatter into preds
        k_skinny<1, 1><<<dim3(157, 1), 256, 0, stream>>>(h, D_, Wout, D_, 1 << 30,
            nullptr, 0, nullptr, 0, V_, D_, 512, out + OFF_PREDS, bout, t, dlen);
    }
}

// Round 2
// 1999.597 us; speedup vs baseline: 2.1018x; 2.1018x over previous
//
#include <hip/hip_runtime.h>

#define B_ 64
#define P_ 196
#define ENC_ 2048
#define L_ 20
#define T_ 19
#define A_ 512
#define D_ 512
#define E_ 512
#define V_ 10000

// output offsets (float elements)
#define OFF_PREDS 0
#define OFF_CAPS  12160000
#define OFF_DLEN  12161280
#define OFF_ALPH  12161344
#define OFF_SIDX  12399680

// workspace offsets (bytes) — total ~55 MB
#define WS_SORT   0
#define WS_DLEN   1024
#define WS_CAPS   2048
#define WS_RIDXE  8192
#define WS_SCORES 61440
#define WS_DAS    114688
#define WS_GATE   245760     /* == WS_DAS + 64*512*4 : EPI2 relies on adjacency */
#define WS_MEAN   770048
#define WS_C      1294336
#define WS_HB     1425408
#define WS_CTXG   1490944
#define WS_PH     1753088
#define WS_PC     2801664
#define WS_GPART  3850240
#define WS_GEMB   5947392
#define WS_EPT    15908864
#define WS_EMB    28753920   /* 1216*512*2 = 1245184 */
#define WS_WEAT   30003200   /* 512*2048*2 = 2097152 */
#define WS_WHG    32100352   /* 2560*512*2 = 2621440 */
#define WS_W2     34721792   /* 2048*2560*2 = 10485760 */
#define WS_WIH1   45207552   /* 2048*512*2 = 2097152 */
#define WS_WOUT   47304704   /* 10048*512*2 = 10289152 -> end 57593856 */

typedef __attribute__((ext_vector_type(8))) short short8v;
typedef __attribute__((ext_vector_type(4))) float f32x4;
typedef unsigned int uint32;
typedef unsigned short ushort16;

__device__ __forceinline__ float ftanh(float x){ float e=__expf(2.f*x); return 1.f-2.f/(e+1.f); }
__device__ __forceinline__ float fsigm(float x){ return 1.f/(1.f+__expf(-x)); }
__device__ __forceinline__ ushort16 f2b(float f){
    uint32 u = __float_as_uint(f);
    uint32 r = (u + 0x7FFFu + ((u >> 16) & 1u)) >> 16;
    return (ushort16)r;
}
__device__ __forceinline__ uint32 pack_b2(float a, float b){
    return (uint32)f2b(a) | ((uint32)f2b(b) << 16);
}
__device__ __forceinline__ float b2f_lo(uint32 w){ return __uint_as_float(w << 16); }
__device__ __forceinline__ float b2f_hi(uint32 w){ return __uint_as_float(w & 0xFFFF0000u); }

// ---------------------------------------------------------------- sort + meta
__global__ void k_sort(const int* __restrict__ cap_len, const int* __restrict__ captions,
                       float* __restrict__ out, int* __restrict__ wsi)
{
    __shared__ int len_s[B_];
    __shared__ int idx_s[B_];
    int tid = threadIdx.x;
    if (tid < B_) { len_s[tid] = cap_len[tid]; idx_s[tid] = tid; }
    __syncthreads();
    if (tid == 0) {
        for (int i = 0; i < B_; ++i) {
            int best = i;
            for (int j = i + 1; j < B_; ++j) {
                if (len_s[j] > len_s[best] ||
                    (len_s[j] == len_s[best] && idx_s[j] < idx_s[best])) best = j;
            }
            int tl = len_s[i]; len_s[i] = len_s[best]; len_s[best] = tl;
            int ti = idx_s[i]; idx_s[i] = idx_s[best]; idx_s[best] = ti;
        }
    }
    __syncthreads();
    int* sortidx = wsi + WS_SORT / 4;
    int* dlen    = wsi + WS_DLEN / 4;
    int* caps    = wsi + WS_CAPS / 4;
    int* ridxe   = wsi + WS_RIDXE / 4;
    if (tid < B_) {
        sortidx[tid] = idx_s[tid];
        int dl = len_s[tid] - 1;
        dlen[tid] = dl;
        out[OFF_SIDX + tid] = (float)idx_s[tid];
        out[OFF_DLEN + tid] = (float)dl;
        for (int l = 0; l < L_; ++l) {
            int cv = captions[idx_s[tid] * L_ + l];
            caps[tid * L_ + l] = cv;
            out[OFF_CAPS + tid * L_ + l] = (float)cv;
        }
    }
    for (int i = tid; i < B_ * P_; i += 64) {
        int bb = i / P_, pp = i % P_;
        ridxe[i] = idx_s[bb] * P_ + pp;
    }
}

// ---------------------------------------------------------------- transpose+cast f32[R][C] -> bf16[C][R]
__global__ __launch_bounds__(256) void k_transpose(const float* __restrict__ src, int R, int C,
                                                   ushort16* __restrict__ dst)
{
    __shared__ float tile[64][65];
    int c0 = blockIdx.x * 64, r0 = blockIdx.y * 64;
    int lx = threadIdx.x & 63, ly = threadIdx.x >> 6;
#pragma unroll
    for (int i = 0; i < 16; ++i) {
        int r = ly * 16 + i;
        tile[lx][r] = src[(long)(r0 + r) * C + c0 + lx];
    }
    __syncthreads();
#pragma unroll
    for (int i = 0; i < 16; ++i) {
        int cr = ly * 16 + i;
        dst[(long)(c0 + cr) * R + r0 + lx] = f2b(tile[cr][lx]);
    }
}

// ---------------------------------------------------------------- strided row cast f32->bf16 (K=512)
__global__ __launch_bounds__(256) void k_cast_rows(const float* __restrict__ src, int sld,
                                                   ushort16* __restrict__ dst, int dld)
{
    int r = blockIdx.x;
    int k = threadIdx.x * 2;
    float2 v = *(const float2*)(src + (long)r * sld + k);
    *(uint32*)(dst + (long)r * dld + k) = pack_b2(v.x, v.y);
}

// ---------------------------------------------------------------- pack W2 = [W_ih[:,512:2560] ; W_hh] bf16 [n][2560]
__global__ __launch_bounds__(256) void k_pack_w2(const float* __restrict__ WIH,
                                                 const float* __restrict__ WHH,
                                                 ushort16* __restrict__ dst)
{
    int n = blockIdx.x;
    for (int cch = threadIdx.x; cch < 320; cch += 256) {
        int kof = cch * 8;
        const float* s = (kof < ENC_) ? (WIH + (long)n * 2560 + 512 + kof)
                                      : (WHH + (long)n * 512 + (kof - ENC_));
        float4 f0 = *(const float4*)s;
        float4 f1 = *(const float4*)(s + 4);
        uint4 v; v.x = pack_b2(f0.x, f0.y); v.y = pack_b2(f0.z, f0.w);
        v.z = pack_b2(f1.x, f1.y); v.w = pack_b2(f1.z, f1.w);
        *(uint4*)(dst + (long)n * 2560 + kof) = v;
    }
}

// ---------------------------------------------------------------- gather+cast embeddings: rows m=t*64+b
__global__ __launch_bounds__(256) void k_cast_emb(const float* __restrict__ embedding,
                                                  const int* __restrict__ caps,
                                                  ushort16* __restrict__ dst)
{
    int m = blockIdx.x;                       // 0..1215
    int tok = caps[(m & 63) * L_ + (m >> 6)];
    int k = threadIdx.x * 2;
    float2 v = *(const float2*)(embedding + (long)tok * E_ + k);
    *(uint32*)(dst + (long)m * E_ + k) = pack_b2(v.x, v.y);
}

// ---------------------------------------------------------------- mean feats (f32)
__global__ __launch_bounds__(256) void k_mean(const float* __restrict__ enc,
                                              const int* __restrict__ wsi,
                                              float* __restrict__ mean)
{
    int b = blockIdx.x;
    int e = blockIdx.y * 256 + threadIdx.x;
    int src = wsi[WS_SORT / 4 + b];
    const float* p = enc + (long)src * P_ * ENC_ + e;
    float s = 0.f;
    for (int i = 0; i < P_; ++i) s += p[(long)i * ENC_];
    mean[b * ENC_ + e] = s * (1.f / (float)P_);
}

// ---------------------------------------------------------------- f32 skinny split-K GEMM (h0/c0 only)
__global__ __launch_bounds__(256) void k_skinny(
    const float* __restrict__ A1, int lda1,
    const float* __restrict__ B1, int ldb1,
    int N, int Kper, float* __restrict__ Cout)
{
    __shared__ float As[16][68];
    __shared__ float Bs[16][68];
    int tid = threadIdx.x;
    int n0 = blockIdx.x * 64;
    int split = blockIdx.y;
    int kbeg = split * Kper;
    int tx = tid & 15, ty = tid >> 4;
    float acc[4][4] = {};
    int am = tid >> 2, akq = (tid & 3) << 2;
    for (int k0 = kbeg; k0 < kbeg + Kper; k0 += 16) {
        float4 av = *(const float4*)(A1 + (long)am * lda1 + k0 + akq);
        As[akq + 0][am] = av.x; As[akq + 1][am] = av.y;
        As[akq + 2][am] = av.z; As[akq + 3][am] = av.w;
        int bk = tid >> 4, bnq = (tid & 15) << 2;
        float4 bv = *(const float4*)(B1 + (long)(k0 + bk) * ldb1 + n0 + bnq);
        Bs[bk][bnq + 0] = bv.x; Bs[bk][bnq + 1] = bv.y;
        Bs[bk][bnq + 2] = bv.z; Bs[bk][bnq + 3] = bv.w;
        __syncthreads();
#pragma unroll
        for (int kk = 0; kk < 16; ++kk) {
            float4 a4 = *(const float4*)&As[kk][ty << 2];
            float4 b4 = *(const float4*)&Bs[kk][tx << 2];
            float aa[4] = {a4.x, a4.y, a4.z, a4.w};
            float bb[4] = {b4.x, b4.y, b4.z, b4.w};
#pragma unroll
            for (int i = 0; i < 4; ++i)
#pragma unroll
                for (int j = 0; j < 4; ++j) acc[i][j] += aa[i] * bb[j];
        }
        __syncthreads();
    }
#pragma unroll
    for (int i = 0; i < 4; ++i) {
        int m = (ty << 2) + i;
#pragma unroll
        for (int j = 0; j < 4; ++j) {
            int gn = n0 + (tx << 2) + j;
            Cout[((long)(split * B_ + m)) * N + gn] = acc[i][j];
        }
    }
}

// ---------------------------------------------------------------- h0/c0 reduce -> h_bf16, c
__global__ __launch_bounds__(256) void k_reduce_hc(
    const float* __restrict__ ph, const float* __restrict__ pc,
    const float* __restrict__ bih, const float* __restrict__ bic,
    ushort16* __restrict__ hb, float* __restrict__ c)
{
    int i = blockIdx.x * 256 + threadIdx.x; // 64*512
    int d = i & (D_ - 1);
    float sh = bih[d], s2 = bic[d];
    for (int s = 0; s < 8; ++s) {
        sh += ph[(long)s * (B_ * D_) + i];
        s2 += pc[(long)s * (B_ * D_) + i];
    }
    hb[i] = f2b(sh); c[i] = s2;
}

// ---------------------------------------------------------------- bf16 MFMA GEMM
template<int BM, int BN, int WM, int WN, int EPI, bool TWOSEG, bool AF32G>
__global__ __launch_bounds__(256) void mgemm(
    const void* __restrict__ A1v, int lda1,
    const void* __restrict__ A2v, int lda2, int Ksw,
    const ushort16* __restrict__ Bmat, int ldb,
    void* __restrict__ Cout, int ldc, int N, int Kper,
    const float* __restrict__ bias, const float* __restrict__ bias2,
    int t, const int* __restrict__ dlen, const int* __restrict__ ridx)
{
    __shared__ __align__(16) ushort16 As[BM * 64];
    __shared__ __align__(16) ushort16 Bs[BN * 64];
    const int tid = threadIdx.x;
    const int m0 = blockIdx.y * BM, n0 = blockIdx.x * BN;
    const int kbeg = blockIdx.z * Kper;
    const int lane = tid & 63, wid = tid >> 6;
    constexpr int NWC = BN / WN;
    const int wr = wid / NWC, wc = wid % NWC;
    constexpr int FM = WM / 16, FN = WN / 16;
    f32x4 acc[FM][FN] = {};

    for (int k0 = kbeg; k0 < kbeg + Kper; k0 += 64) {
        for (int i = tid; i < BM * 8; i += 256) {
            int r = i >> 3, ck = i & 7;
            int kk = k0 + ck * 8;
            uint4 val;
            if (AF32G) {
                const float* src = (const float*)A1v + (long)ridx[m0 + r] * lda1 + kk;
                float4 f0 = *(const float4*)src;
                float4 f1 = *(const float4*)(src + 4);
                val.x = pack_b2(f0.x, f0.y); val.y = pack_b2(f0.z, f0.w);
                val.z = pack_b2(f1.x, f1.y); val.w = pack_b2(f1.z, f1.w);
            } else {
                const ushort16* src;
                if (!TWOSEG || kk < Ksw) src = (const ushort16*)A1v + (long)(m0 + r) * lda1 + kk;
                else                     src = (const ushort16*)A2v + (long)(m0 + r) * lda2 + (kk - Ksw);
                val = *(const uint4*)src;
            }
            int bo = (r * 128 + ck * 16) ^ ((r & 7) << 4);
            *(uint4*)((char*)As + bo) = val;
        }
        for (int i = tid; i < BN * 8; i += 256) {
            int r = i >> 3, ck = i & 7;
            int kk = k0 + ck * 8;
            uint4 val = *(const uint4*)(Bmat + (long)(n0 + r) * ldb + kk);
            int bo = (r * 128 + ck * 16) ^ ((r & 7) << 4);
            *(uint4*)((char*)Bs + bo) = val;
        }
        __syncthreads();
#pragma unroll
        for (int kk = 0; kk < 64; kk += 32) {
            short8v af[FM], bfr[FN];
#pragma unroll
            for (int f = 0; f < FM; ++f) {
                int r = wr * WM + f * 16 + (lane & 15);
                int bo = (r * 128 + (kk + ((lane >> 4) << 3)) * 2) ^ ((r & 7) << 4);
                af[f] = *(const short8v*)((const char*)As + bo);
            }
#pragma unroll
            for (int f = 0; f < FN; ++f) {
                int r = wc * WN + f * 16 + (lane & 15);
                int bo = (r * 128 + (kk + ((lane >> 4) << 3)) * 2) ^ ((r & 7) << 4);
                bfr[f] = *(const short8v*)((const char*)Bs + bo);
            }
#pragma unroll
            for (int fm = 0; fm < FM; ++fm)
#pragma unroll
                for (int fn = 0; fn < FN; ++fn)
                    acc[fm][fn] = __builtin_amdgcn_mfma_f32_16x16x32_bf16(
                        af[fm], bfr[fn], acc[fm][fn], 0, 0, 0);
        }
        __syncthreads();
    }

    int rr = lane >> 4, cc = lane & 15;
#pragma unroll
    for (int fm = 0; fm < FM; ++fm) {
#pragma unroll
        for (int fn = 0; fn < FN; ++fn) {
#pragma unroll
            for (int r = 0; r < 4; ++r) {
                int gm = m0 + wr * WM + fm * 16 + rr * 4 + r;
                int gn = n0 + wc * WN + fn * 16 + cc;
                float v = acc[fm][fn][r];
                if (EPI == 0) {
                    if (bias)  v += bias[gn];
                    if (bias2) v += bias2[gn];
                    ((float*)Cout)[(long)gm * ldc + gn] = v;
                } else if (EPI == 1) {
                    ((ushort16*)Cout)[(long)gm * ldc + gn] = f2b(v + bias[gn]);
                } else if (EPI == 2) {
                    if (gn < 512) ((float*)Cout)[gm * 512 + gn] = v + bias[gn];
                    else ((float*)Cout)[B_ * 512 + gm * ENC_ + (gn - 512)] =
                             fsigm(v + bias2[gn - 512]);
                } else if (EPI == 3) {
                    ((float*)Cout)[((long)(blockIdx.z * B_ + gm)) * ldc + gn] = v;
                } else if (EPI == 4) {
                    if (gn < N && t < dlen[gm])
                        ((float*)Cout)[((long)gm * T_ + t) * V_ + gn] = v + bias[gn];
                }
            }
        }
    }
}

// ---------------------------------------------------------------- scores: wf . tanh(ept + das)
__global__ __launch_bounds__(256) void k_score(
    const ushort16* __restrict__ ept, const float* __restrict__ das,
    const float* __restrict__ wf, const float* __restrict__ bf,
    const int* __restrict__ dlen, float* __restrict__ scores, int t)
{
    int b = blockIdx.x;
    if (t >= dlen[b]) return;
    int pg = blockIdx.y;
    int tid = threadIdx.x, lane = tid & 63, w = tid >> 6;
    float wf8[8], da8[8];
    const float* wp = wf + lane * 8;
    const float* dp = das + b * 512 + lane * 8;
#pragma unroll
    for (int j = 0; j < 8; ++j) { wf8[j] = wp[j]; da8[j] = dp[j]; }
    float b0 = bf[0];
    for (int pl = w; pl < 49; pl += 4) {
        int p = pg * 49 + pl;
        uint4 u = *(const uint4*)(ept + ((long)(b * P_ + p)) * 512 + lane * 8);
        float s = 0.f;
        s += wf8[0] * ftanh(b2f_lo(u.x) + da8[0]);
        s += wf8[1] * ftanh(b2f_hi(u.x) + da8[1]);
        s += wf8[2] * ftanh(b2f_lo(u.y) + da8[2]);
        s += wf8[3] * ftanh(b2f_hi(u.y) + da8[3]);
        s += wf8[4] * ftanh(b2f_lo(u.z) + da8[4]);
        s += wf8[5] * ftanh(b2f_hi(u.z) + da8[5]);
        s += wf8[6] * ftanh(b2f_lo(u.w) + da8[6]);
        s += wf8[7] * ftanh(b2f_hi(u.w) + da8[7]);
#pragma unroll
        for (int off = 32; off > 0; off >>= 1) s += __shfl_xor(s, off);
        if (lane == 0) scores[b * P_ + p] = s + b0;
    }
}

// ---------------------------------------------------------------- softmax + gated context
__global__ __launch_bounds__(256) void k_ctx(
    const float* __restrict__ scores, const float* __restrict__ gate,
    const float* __restrict__ enc, const int* __restrict__ wsi,
    const int* __restrict__ dlen, ushort16* __restrict__ ctxg,
    float* __restrict__ out, int t)
{
    int b = blockIdx.x;
    if (t >= dlen[b]) return;
    __shared__ float red[256];
    __shared__ float al[P_ + 4];
    int tid = threadIdx.x;
    float sc = (tid < P_) ? scores[b * P_ + tid] : -1e30f;
    red[tid] = sc;
    __syncthreads();
    for (int s = 128; s > 0; s >>= 1) {
        if (tid < s) red[tid] = fmaxf(red[tid], red[tid + s]);
        __syncthreads();
    }
    float mx = red[0];
    __syncthreads();
    float e = (tid < P_) ? __expf(sc - mx) : 0.f;
    red[tid] = e;
    __syncthreads();
    for (int s = 128; s > 0; s >>= 1) {
        if (tid < s) red[tid] += red[tid + s];
        __syncthreads();
    }
    float inv = 1.f / red[0];
    if (tid < P_) al[tid] = e * inv;
    __syncthreads();
    if (blockIdx.y == 0 && tid < P_)
        out[OFF_ALPH + ((long)b * T_ + t) * P_ + tid] = al[tid];
    int ei = blockIdx.y * 256 + tid;
    long base = ((long)wsi[WS_SORT / 4 + b] * P_) * ENC_ + ei;
    float cv = 0.f;
#pragma unroll 4
    for (int p = 0; p < P_; ++p) cv += al[p] * enc[base + (long)p * ENC_];
    ctxg[b * ENC_ + ei] = f2b(gate[b * ENC_ + ei] * cv);
}

// ---------------------------------------------------------------- LSTM pointwise
__global__ __launch_bounds__(256) void k_lstm(
    const float* __restrict__ gemb, const float* __restrict__ gpart,
    const int* __restrict__ dlen, float* __restrict__ c,
    ushort16* __restrict__ hb, int t)
{
    int b = blockIdx.x;
    if (t >= dlen[b]) return;
    int d = blockIdx.y * 256 + threadIdx.x;
    const float* ge = gemb + ((long)(t * B_ + b)) * ENC_;
    float g[4];
#pragma unroll
    for (int q = 0; q < 4; ++q) {
        int j = q * D_ + d;
        float v = ge[j];
        for (int s = 0; s < 4; ++s) v += gpart[((long)(s * B_ + b)) * ENC_ + j];
        g[q] = v;
    }
    float i_ = fsigm(g[0]), f_ = fsigm(g[1]), gg = ftanh(g[2]), o_ = fsigm(g[3]);
    long off = (long)b * D_ + d;
    float cn = f_ * c[off] + i_ * gg;
    float hn = o_ * ftanh(cn);
    c[off] = cn; hb[off] = f2b(hn);
}

// ---------------------------------------------------------------- launch
extern "C" void kernel_launch(void* const* d_in, const int* in_sizes, int n_in,
                              void* d_out, int out_size, void* d_ws, size_t ws_size,
                              hipStream_t stream)
{
    (void)in_sizes; (void)n_in; (void)out_size; (void)ws_size;
    const float* enc      = (const float*)d_in[0];
    const int*   captions = (const int*)d_in[1];
    const int*   caplen   = (const int*)d_in[2];
    const float* Wemb     = (const float*)d_in[3];
    const float* Wea = (const float*)d_in[4];  const float* bea = (const float*)d_in[5];
    const float* Wda = (const float*)d_in[6];  const float* bda = (const float*)d_in[7];
    const float* Wfa = (const float*)d_in[8];  const float* bfa = (const float*)d_in[9];
    const float* Wih = (const float*)d_in[10]; const float* bih = (const float*)d_in[11];
    const float* Wic = (const float*)d_in[12]; const float* bic = (const float*)d_in[13];
    const float* Wbe = (const float*)d_in[14]; const float* bbe = (const float*)d_in[15];
    const float* WIH = (const float*)d_in[16]; const float* bIH = (const float*)d_in[17];
    const float* WHH = (const float*)d_in[18]; const float* bHH = (const float*)d_in[19];
    const float* Wout = (const float*)d_in[20]; const float* bout = (const float*)d_in[21];

    float* out = (float*)d_out;
    char*  ws  = (char*)d_ws;
    int*   wsi = (int*)ws;
    const int* dlen = wsi + WS_DLEN / 4;
    float* scores = (float*)(ws + WS_SCORES);
    float* das    = (float*)(ws + WS_DAS);
    float* gate   = (float*)(ws + WS_GATE);
    float* mean   = (float*)(ws + WS_MEAN);
    float* c      = (float*)(ws + WS_C);
    ushort16* hb  = (ushort16*)(ws + WS_HB);
    ushort16* ctxg= (ushort16*)(ws + WS_CTXG);
    float* ph     = (float*)(ws + WS_PH);
    float* pc     = (float*)(ws + WS_PC);
    float* gpart  = (float*)(ws + WS_GPART);
    float* gemb   = (float*)(ws + WS_GEMB);
    ushort16* ept = (ushort16*)(ws + WS_EPT);
    ushort16* embB= (ushort16*)(ws + WS_EMB);
    ushort16* WeaT= (ushort16*)(ws + WS_WEAT);
    ushort16* Whg = (ushort16*)(ws + WS_WHG);
    ushort16* W2  = (ushort16*)(ws + WS_W2);
    ushort16* Wih1= (ushort16*)(ws + WS_WIH1);
    ushort16* WoB = (ushort16*)(ws + WS_WOUT);

    hipMemsetAsync(out, 0, (size_t)OFF_CAPS * 4, stream);
    hipMemsetAsync(out + OFF_ALPH, 0, (size_t)(B_ * T_ * P_) * 4, stream);

    k_sort<<<1, 64, 0, stream>>>(caplen, captions, out, wsi);
    // weight prep (one-time)
    k_transpose<<<dim3(8, 32), 256, 0, stream>>>(Wea, ENC_, A_, WeaT);             // WeaT[a][e]
    k_transpose<<<dim3(8, 8),  256, 0, stream>>>(Wda, D_, A_, Whg);                // Whg rows 0..511
    k_transpose<<<dim3(32, 8), 256, 0, stream>>>(Wbe, D_, ENC_, Whg + 512 * 512);  // Whg rows 512..2559
    k_pack_w2<<<2048, 256, 0, stream>>>(WIH, WHH, W2);
    k_cast_rows<<<2048, 256, 0, stream>>>(WIH, 2560, Wih1, 512);
    k_cast_rows<<<10000, 256, 0, stream>>>(Wout, 512, WoB, 512);
    k_cast_emb<<<1216, 256, 0, stream>>>(Wemb, wsi + WS_CAPS / 4, embB);

    // h0/c0
    k_mean<<<dim3(64, 8), 256, 0, stream>>>(enc, wsi, mean);
    k_skinny<<<dim3(8, 8), 256, 0, stream>>>(mean, ENC_, Wih, D_, D_, 256, ph);
    k_skinny<<<dim3(8, 8), 256, 0, stream>>>(mean, ENC_, Wic, D_, D_, 256, pc);
    k_reduce_hc<<<128, 256, 0, stream>>>(ph, pc, bih, bic, hb, c);

    // enc_proj -> ept bf16 [b][p][a]
    mgemm<128, 128, 64, 64, 1, false, true><<<dim3(4, 98, 1), 256, 0, stream>>>(
        enc, ENC_, nullptr, 0, 1 << 30, WeaT, ENC_,
        ept, A_, A_, ENC_, bea, nullptr, 0, nullptr, wsi + WS_RIDXE / 4);
    // gates_emb = emb @ W_ih[:, :512].T + bIH + bHH, rows m = t*64+b
    mgemm<64, 64, 32, 32, 0, false, false><<<dim3(32, 19, 1), 256, 0, stream>>>(
        embB, E_, nullptr, 0, 1 << 30, Wih1, E_,
        gemb, ENC_, ENC_, E_, bIH, bHH, 0, nullptr, nullptr);

    for (int t = 0; t < T_; ++t) {
        // das | beta-gate
        mgemm<64, 64, 32, 32, 2, false, false><<<dim3(40, 1, 1), 256, 0, stream>>>(
            hb, D_, nullptr, 0, 1 << 30, Whg, D_,
            das, 0, 2560, D_, bda, bbe, t, nullptr, nullptr);
        k_score<<<dim3(64, 4), 256, 0, stream>>>(ept, das, Wfa, bfa, dlen, scores, t);
        k_ctx<<<dim3(64, 8), 256, 0, stream>>>(scores, gate, enc, wsi, dlen, ctxg, out, t);
        // LSTM gates: [ctxg | h] @ [W_ih[:,512:]; W_hh]^T, split-K=4
        mgemm<64, 64, 32, 32, 3, true, false><<<dim3(32, 1, 4), 256, 0, stream>>>(
            ctxg, ENC_, hb, D_, ENC_, W2, 2560,
            gpart, ENC_, ENC_, 640, nullptr, nullptr, t, nullptr, nullptr);
        k_lstm<<<dim3(64, 2), 256, 0, stream>>>(gemb, gpart, dlen, c, hb, t);
        // pred = h_new @ W_out^T + b_out (masked scatter)
        mgemm<64, 64, 32, 32, 4, false, false><<<dim3(157, 1, 1), 256, 0, stream>>>(
            hb, D_, nullptr, 0, 1 << 30, WoB, D_,
            out + OFF_PREDS, 0, V_, D_, bout, nullptr, t, dlen, nullptr);
    }
}